// Round 9
// baseline (342.469 us; speedup 1.0000x reference)
//
#include <hip/hip_runtime.h>
#include <hip/hip_bf16.h>

// Round-2 finding: ALL inputs and the output are FP32.
// Round-8 post-mortem: conv_mfma was latency-serialized (VGPR_Count=28 ->
// compiler minimized regs, no load pipelining; MfmaUtil 3.6%, all pipes
// idle).  Round 9: depth-4 explicit prefetch + __launch_bounds__(256,4)
// (128-VGPR cap) in conv_mfma.  Everything else unchanged.

typedef __hip_bfloat16 bf16;
using short8 = __attribute__((ext_vector_type(8))) short;
using short4v = __attribute__((ext_vector_type(4))) short;
using f32x4 = __attribute__((ext_vector_type(4))) float;

__device__ __forceinline__ short f2bs(float f) {
  union { bf16 b; short s; } u; u.b = __float2bfloat16(f); return u.s;
}
__device__ __forceinline__ float bs2f(short s) {
  union { unsigned u; float f; } x; x.u = ((unsigned)(unsigned short)s) << 16;
  return x.f;
}

// ---------------------------------------------------------------------------
// Prepass A: xt[b][34][34][256] bf16 = x NCHW -> spatial-major channel-contig
// with zero halo ring (conv padding by layout).  grid (8, 34), block 256.
// ---------------------------------------------------------------------------
__global__ __launch_bounds__(256) void xpose(
    const float* __restrict__ X, short* __restrict__ xt) {
  const int b = blockIdx.x, r = blockIdx.y;   // r in 0..33 (halo coords)
  const int tid = threadIdx.x;
  const bool rin = (r >= 1) && (r <= 32);
  for (int idx = tid; idx < 34 * 256; idx += 256) {
    int cc = idx >> 8, c = idx & 255;
    float v = 0.f;
    if (rin && cc >= 1 && cc <= 32)
      v = X[((size_t)b * 256 + c) * 1024 + (r - 1) * 32 + (cc - 1)];
    xt[(((size_t)b * 34 + r) * 34 + cc) * 256 + c] = f2bs(v);
  }
}

// ---------------------------------------------------------------------------
// Prepass B: Wb[tap][o][c] bf16 from w_out[o][c][3][3].  589824 elements.
// grid 2304, block 256.
// ---------------------------------------------------------------------------
__global__ __launch_bounds__(256) void wpack(
    const float* __restrict__ Wc, short* __restrict__ Wb) {
  int idx = blockIdx.x * 256 + threadIdx.x;   // tap*65536 + o*256 + c
  int tap = idx >> 16;
  int rest = idx & 65535;
  int o = rest >> 8, c = rest & 255;
  Wb[idx] = f2bs(Wc[((size_t)o * 256 + c) * 9 + tap]);
}

// ---------------------------------------------------------------------------
// Kernel 1: QKV 1x1 conv as GEMM.  Epilogue emits MFMA-ready bf16:
//   qsb[bnh][q][d] (scaled) | ksb[bnh][key][d] | vtb[bnh][d][key]
// grid (16, 12, 8), block 256.
// ---------------------------------------------------------------------------
__global__ __launch_bounds__(256) void qkv_gemm(
    const float* __restrict__ W, const float* __restrict__ X,
    const float* __restrict__ bias,
    short* __restrict__ qsb, short* __restrict__ ksb, short* __restrict__ vtb) {
  const int b  = blockIdx.z;
  const int p0 = blockIdx.x * 64;
  const int o0 = blockIdx.y * 64;
  const int tid = threadIdx.x;
  const int tx = tid & 15, ty = tid >> 4;
  __shared__ float As[16][64];   // [k][o]
  __shared__ float Bs[16][64];   // [k][p]
  float acc[4][4] = {};
  const float* Xb = X + (size_t)b * 256 * 1024;
  for (int c0 = 0; c0 < 256; c0 += 16) {
    {
      int r = tid >> 2, c4 = (tid & 3) * 4;
      float4 w4 = *(const float4*)(W + (size_t)(o0 + r) * 256 + c0 + c4);
      As[c4 + 0][r] = w4.x; As[c4 + 1][r] = w4.y;
      As[c4 + 2][r] = w4.z; As[c4 + 3][r] = w4.w;
    }
    {
      int r = tid >> 4, cp = (tid & 15) * 4;
      float4 x4 = *(const float4*)(Xb + (size_t)(c0 + r) * 1024 + p0 + cp);
      *(float4*)&Bs[r][cp] = x4;
    }
    __syncthreads();
#pragma unroll
    for (int k = 0; k < 16; ++k) {
      float4 a4 = *(const float4*)&As[k][ty * 4];
      float4 b4 = *(const float4*)&Bs[k][tx * 4];
      float av[4] = {a4.x, a4.y, a4.z, a4.w};
      float bv[4] = {b4.x, b4.y, b4.z, b4.w};
#pragma unroll
      for (int i2 = 0; i2 < 4; ++i2)
#pragma unroll
        for (int j2 = 0; j2 < 4; ++j2)
          acc[i2][j2] += av[i2] * bv[j2];
    }
    __syncthreads();
  }
  const float scale = 0.17677669529663687f;  // 32^-0.5
#pragma unroll
  for (int i2 = 0; i2 < 4; ++i2) {
    int o = o0 + ty * 4 + i2;
    float bv = bias[o];
    int sect = o >> 8;                       // 0=q 1=k 2=v (block-uniform)
    int nh = (o >> 5) & 7, d = o & 31;
    size_t hb = ((size_t)(b * 8 + nh)) * 1024;   // bnh * 1024
    if (sect == 0) {
#pragma unroll
      for (int j2 = 0; j2 < 4; ++j2) {
        int p = p0 + tx * 4 + j2;
        qsb[(hb + p) * 32 + d] = f2bs((acc[i2][j2] + bv) * scale);
      }
    } else if (sect == 1) {
#pragma unroll
      for (int j2 = 0; j2 < 4; ++j2) {
        int p = p0 + tx * 4 + j2;
        ksb[(hb + p) * 32 + d] = f2bs(acc[i2][j2] + bv);
      }
    } else {
#pragma unroll
      for (int j2 = 0; j2 < 4; ++j2) {
        int p = p0 + tx * 4 + j2;
        vtb[hb * 32 + (size_t)d * 1024 + p] = f2bs(acc[i2][j2] + bv);
      }
    }
  }
}

// ---------------------------------------------------------------------------
// Kernel 2: MFMA flash attention (round 7, unchanged).  grid (16, 64),
// block 256 = 4 waves; 1 wave = 16 queries x 1024 keys.
// ---------------------------------------------------------------------------
__global__ __launch_bounds__(256, 4) void attn_mfma(
    const short* __restrict__ qsb, const short* __restrict__ ksb,
    const short* __restrict__ vtb,
    const float* __restrict__ relw_g, const float* __restrict__ relh_g,
    float* __restrict__ am) {
  const int tid = threadIdx.x;
  const int w = tid >> 6, lane = tid & 63;
  const int col = lane & 15, grp = lane >> 4;
  const int g8 = grp * 8;
  const int qt = blockIdx.x * 4 + w;       // q-tile 0..63
  const int bnh = blockIdx.y;
  const int q0 = qt * 16;
  const int i = qt >> 1;                   // query row, constant per wave
  const int j0 = (qt & 1) * 16;            // query col base

  const short* Qb = qsb + (size_t)bnh * 32768;
  const short* Kb = ksb + (size_t)bnh * 32768;
  const short* Vb = vtb + (size_t)bnh * 32768;

  __shared__ short Gh_s[4][64][16];  // [wave][m][q]  8KB
  __shared__ short Gw_s[4][64][16];  // [wave][m][q]  8KB
  __shared__ short P_s[4][16][40];   // [wave][q][key] pitch 40  5KB

  short8 a_q = *(const short8*)(Qb + (q0 + col) * 32 + g8);

  {
    const float* rels[2] = {relh_g, relw_g};
    short* gbase[2] = {&Gh_s[w][0][0], &Gw_s[w][0][0]};
#pragma unroll
    for (int tb = 0; tb < 2; ++tb) {
      const float* relg = rels[tb];
      short* Gb = gbase[tb];
#pragma unroll
      for (int t = 0; t < 4; ++t) {
        int m = col + 16 * t;
        int mc = m > 62 ? 62 : m;            // m=63 is junk, never read
        const float* rp = relg + mc * 32 + g8;
        float4 f0 = *(const float4*)rp;
        float4 f1 = *(const float4*)(rp + 4);
        short8 br;
        br[0] = f2bs(f0.x); br[1] = f2bs(f0.y);
        br[2] = f2bs(f0.z); br[3] = f2bs(f0.w);
        br[4] = f2bs(f1.x); br[5] = f2bs(f1.y);
        br[6] = f2bs(f1.z); br[7] = f2bs(f1.w);
        f32x4 d = __builtin_amdgcn_mfma_f32_16x16x32_bf16(
            a_q, br, (f32x4){0.f, 0.f, 0.f, 0.f}, 0, 0, 0);
        short4v o;
        o[0] = f2bs(d[0]); o[1] = f2bs(d[1]);
        o[2] = f2bs(d[2]); o[3] = f2bs(d[3]);
        *(short4v*)(Gb + m * 16 + grp * 4) = o;
      }
    }
  }
  __asm__ volatile("s_waitcnt lgkmcnt(0)" ::: "memory");

  short one_v = (col == 0) ? (short)0x3F80 : (short)0;
  short8 b_one = {one_v, one_v, one_v, one_v, one_v, one_v, one_v, one_v};

  f32x4 acc0 = {0.f, 0.f, 0.f, 0.f};
  f32x4 acc1 = {0.f, 0.f, 0.f, 0.f};
  f32x4 accl = {0.f, 0.f, 0.f, 0.f};

  short8 k0 = *(const short8*)(Kb + (0 * 32 + 0 * 16 + col) * 32 + g8);
  short8 k1 = *(const short8*)(Kb + (0 * 32 + 1 * 16 + col) * 32 + g8);
  short8 v0 = *(const short8*)(Vb + (0 * 16 + col) * 1024 + 0 * 32 + g8);
  short8 v1 = *(const short8*)(Vb + (1 * 16 + col) * 1024 + 0 * 32 + g8);

#pragma unroll 1
  for (int c = 0; c < 32; ++c) {
    short8 ck0 = k0, ck1 = k1, cv0 = v0, cv1 = v1;
    if (c + 1 < 32) {
      int kb = (c + 1) * 32;
      k0 = *(const short8*)(Kb + (kb + col) * 32 + g8);
      k1 = *(const short8*)(Kb + (kb + 16 + col) * 32 + g8);
      v0 = *(const short8*)(Vb + (0 * 16 + col) * 1024 + kb + g8);
      v1 = *(const short8*)(Vb + (1 * 16 + col) * 1024 + kb + g8);
    }
    f32x4 s0 = __builtin_amdgcn_mfma_f32_16x16x32_bf16(
        a_q, ck0, (f32x4){0.f, 0.f, 0.f, 0.f}, 0, 0, 0);
    f32x4 s1 = __builtin_amdgcn_mfma_f32_16x16x32_bf16(
        a_q, ck1, (f32x4){0.f, 0.f, 0.f, 0.f}, 0, 0, 0);
    int mh = c - i + 31;
    short4v ghv = *(const short4v*)&Gh_s[w][mh][grp * 4];
#pragma unroll
    for (int t = 0; t < 2; ++t) {
      f32x4 s = t ? s1 : s0;
      int y = t * 16 + col;
#pragma unroll
      for (int r = 0; r < 4; ++r) {
        int qrel = grp * 4 + r;
        int mw = y - j0 - qrel + 31;
        float lg = s[r] + bs2f(ghv[r]) + bs2f(Gw_s[w][mw][qrel]);
        P_s[w][qrel][y] = f2bs(__expf(lg));
      }
    }
    __asm__ volatile("s_waitcnt lgkmcnt(0)" ::: "memory");
    short8 a_p = *(const short8*)&P_s[w][col][g8];
    acc0 = __builtin_amdgcn_mfma_f32_16x16x32_bf16(a_p, cv0, acc0, 0, 0, 0);
    acc1 = __builtin_amdgcn_mfma_f32_16x16x32_bf16(a_p, cv1, acc1, 0, 0, 0);
    accl = __builtin_amdgcn_mfma_f32_16x16x32_bf16(a_p, b_one, accl, 0, 0, 0);
  }

  float* amb = am + (size_t)bnh * 32768;
#pragma unroll
  for (int r = 0; r < 4; ++r) {
    float lv = __shfl(accl[r], lane & 48);
    float rn = 1.0f / lv;
    int q = q0 + grp * 4 + r;
    amb[(size_t)col * 1024 + q] = acc0[r] * rn;
    amb[(size_t)(16 + col) * 1024 + q] = acc1[r] * rn;
  }
}

// ---------------------------------------------------------------------------
// Kernel 3: output projection GEMM, fp32 out channels [256,512).
// grid (16, 4, 8), block 256.
// ---------------------------------------------------------------------------
__global__ __launch_bounds__(256) void proj_gemm(
    const float* __restrict__ W, const float* __restrict__ Am,
    const float* __restrict__ bias, float* __restrict__ out) {
  const int b = blockIdx.z;
  const int p0 = blockIdx.x * 64;
  const int o0 = blockIdx.y * 64;
  const int tid = threadIdx.x;
  const int tx = tid & 15, ty = tid >> 4;
  __shared__ float As[16][64];
  __shared__ float Bs[16][64];
  float acc[4][4] = {};
  const float* Ab = Am + (size_t)b * 256 * 1024;
  for (int c0 = 0; c0 < 256; c0 += 16) {
    {
      int r = tid >> 2, c4 = (tid & 3) * 4;
      float4 w4 = *(const float4*)(W + (size_t)(o0 + r) * 256 + c0 + c4);
      As[c4 + 0][r] = w4.x; As[c4 + 1][r] = w4.y;
      As[c4 + 2][r] = w4.z; As[c4 + 3][r] = w4.w;
    }
    {
      int r = tid >> 4, cp = (tid & 15) * 4;
      float4 x4 = *(const float4*)(Ab + (size_t)(c0 + r) * 1024 + p0 + cp);
      *(float4*)&Bs[r][cp] = x4;
    }
    __syncthreads();
#pragma unroll
    for (int k = 0; k < 16; ++k) {
      float4 a4 = *(const float4*)&As[k][ty * 4];
      float4 b4 = *(const float4*)&Bs[k][tx * 4];
      float av[4] = {a4.x, a4.y, a4.z, a4.w};
      float bv[4] = {b4.x, b4.y, b4.z, b4.w};
#pragma unroll
      for (int i2 = 0; i2 < 4; ++i2)
#pragma unroll
        for (int j2 = 0; j2 < 4; ++j2)
          acc[i2][j2] += av[i2] * bv[j2];
    }
    __syncthreads();
  }
#pragma unroll
  for (int i2 = 0; i2 < 4; ++i2) {
    int o = o0 + ty * 4 + i2;
    float bv = bias[o];
    float4 r4 = make_float4(acc[i2][0] + bv, acc[i2][1] + bv,
                            acc[i2][2] + bv, acc[i2][3] + bv);
    *(float4*)&out[((size_t)b * 512 + 256 + o) * 1024 + p0 + tx * 4] = r4;
  }
}

// ---------------------------------------------------------------------------
// Kernel 4 (v3): MFMA implicit-GEMM 3x3 conv with depth-4 explicit prefetch.
// grid (32 rows, 4 o-quads, 8 b), block 256 = 4 waves; 1 wave = 16 out-ch x
// 32 positions.  Flattened it = tap*8 + chunk (72 iters); u=(tap*11)>>5,
// v=tap-3u (divide-free).  Circular 4-slot prefetch: ~12 loads in flight per
// wave; __launch_bounds__(256,4) caps VGPR at 128 (round-8: default bounds
// gave 28 VGPR -> full latency serialization, MfmaUtil 3.6%).
// ---------------------------------------------------------------------------
__global__ __launch_bounds__(256, 4) void conv_mfma(
    const short* __restrict__ xt, const short* __restrict__ Wb,
    const float* __restrict__ bias, float* __restrict__ out) {
  const int tid = threadIdx.x;
  const int w = tid >> 6, lane = tid & 63;
  const int col = lane & 15, grp = lane >> 4, g8 = grp * 8;
  const int r0 = blockIdx.x;                 // image row 0..31
  const int o0 = blockIdx.y * 64 + w * 16;   // out-channel tile
  const int bb = blockIdx.z;
  const short* Xb = xt + (size_t)bb * 34 * 34 * 256;

  const int aoff = (o0 + col) * 256 + g8;    // + tap*65536 + ch*32
  const int boff = col * 256 + g8;           // + ((r0+u)*34 + v)*256 + ch*32

  short8 A[4], B0[4], B1[4];
#pragma unroll
  for (int s = 0; s < 4; ++s) {              // it = s: tap=0 (u=0,v=0), ch=s
    A[s] = *(const short8*)(Wb + aoff + s * 32);
    const short* pb = Xb + (r0 * 34) * 256 + boff + s * 32;
    B0[s] = *(const short8*)pb;
    B1[s] = *(const short8*)(pb + 16 * 256);
  }

  f32x4 acc0 = {0.f, 0.f, 0.f, 0.f};
  f32x4 acc1 = {0.f, 0.f, 0.f, 0.f};
#pragma unroll 1
  for (int base = 0; base < 72; base += 4) {
#pragma unroll
    for (int s = 0; s < 4; ++s) {
      short8 ca = A[s], cb0 = B0[s], cb1 = B1[s];
      int nx = base + 4 + s;
      if (nx < 72) {
        int tap = nx >> 3, ch = nx & 7;
        int u = (tap * 11) >> 5, v = tap - 3 * u;   // exact for tap<9
        A[s] = *(const short8*)(Wb + tap * 65536 + aoff + ch * 32);
        const short* pb = Xb + ((r0 + u) * 34 + v) * 256 + boff + ch * 32;
        B0[s] = *(const short8*)pb;
        B1[s] = *(const short8*)(pb + 16 * 256);
      }
      acc0 = __builtin_amdgcn_mfma_f32_16x16x32_bf16(ca, cb0, acc0, 0, 0, 0);
      acc1 = __builtin_amdgcn_mfma_f32_16x16x32_bf16(ca, cb1, acc1, 0, 0, 0);
    }
  }

  float* ob = out + (size_t)bb * 512 * 1024;
#pragma unroll
  for (int r = 0; r < 4; ++r) {
    int o = o0 + grp * 4 + r;
    float bv = bias[o];
    ob[(size_t)o * 1024 + r0 * 32 + col]      = acc0[r] + bv;
    ob[(size_t)o * 1024 + r0 * 32 + 16 + col] = acc1[r] + bv;
  }
}

// ---------------------------------------------------------------------------
extern "C" void kernel_launch(void* const* d_in, const int* in_sizes, int n_in,
                              void* d_out, int out_size, void* d_ws, size_t ws_size,
                              hipStream_t stream) {
  const float* x      = (const float*)d_in[0];
  const float* w_qkv  = (const float*)d_in[1];
  const float* b_qkv  = (const float*)d_in[2];
  const float* w_attn = (const float*)d_in[3];
  const float* b_attn = (const float*)d_in[4];
  const float* w_out  = (const float*)d_in[5];
  const float* b_out  = (const float*)d_in[6];
  const float* relw   = (const float*)d_in[7];
  const float* relh   = (const float*)d_in[8];
  float* out = (float*)d_out;

  // ws: qsb bf16 4MB | ksb 4MB | vtb 4MB | am f32 8MB | xt bf16 ~4.74MB
  //     (at 20MB) | Wb bf16 ~1.18MB (at 25MB).  Total ~26.2MB.
  short* qsb = (short*)d_ws;
  short* ksb = qsb + (size_t)2 * 1024 * 1024;
  short* vtb = ksb + (size_t)2 * 1024 * 1024;
  float* am  = (float*)((char*)d_ws + (size_t)12 * 1024 * 1024);
  short* xt  = (short*)((char*)d_ws + (size_t)20 * 1024 * 1024);
  short* Wb  = (short*)((char*)d_ws + (size_t)25 * 1024 * 1024);

  xpose<<<dim3(8, 34), 256, 0, stream>>>(x, xt);
  wpack<<<2304, 256, 0, stream>>>(w_out, Wb);
  qkv_gemm<<<dim3(16, 12, 8), 256, 0, stream>>>(w_qkv, x, b_qkv, qsb, ksb, vtb);
  attn_mfma<<<dim3(16, 64), 256, 0, stream>>>(qsb, ksb, vtb, relw, relh, am);
  proj_gemm<<<dim3(16, 4, 8), 256, 0, stream>>>(w_attn, am, b_attn, out);
  conv_mfma<<<dim3(32, 4, 8), 256, 0, stream>>>(xt, Wb, b_out, out);
}

// Round 10
// 302.241 us; speedup vs baseline: 1.1331x; 1.1331x over previous
//
#include <hip/hip_runtime.h>
#include <hip/hip_bf16.h>

// Round-2 finding: ALL inputs and the output are FP32.
// Round-9 post-mortem: circular-buffer ARRAYS + in-loop conditional made the
// allocator spill every prefetch slot to scratch (WRITE_SIZE 8MB -> 154MB,
// the spill signature; VGPR capped at 64).  Round 10: same depth-3 pipeline
// as NAMED registers, tail-peeled (zero conditionals in the loop),
// __launch_bounds__(256,3) so the budget (~168) far exceeds demand (~80).

typedef __hip_bfloat16 bf16;
using short8 = __attribute__((ext_vector_type(8))) short;
using short4v = __attribute__((ext_vector_type(4))) short;
using f32x4 = __attribute__((ext_vector_type(4))) float;

__device__ __forceinline__ short f2bs(float f) {
  union { bf16 b; short s; } u; u.b = __float2bfloat16(f); return u.s;
}
__device__ __forceinline__ float bs2f(short s) {
  union { unsigned u; float f; } x; x.u = ((unsigned)(unsigned short)s) << 16;
  return x.f;
}

// ---------------------------------------------------------------------------
// Prepass A: xt[b][34][34][256] bf16 = x NCHW -> spatial-major channel-contig
// with zero halo ring (conv padding by layout).  grid (8, 34), block 256.
// ---------------------------------------------------------------------------
__global__ __launch_bounds__(256) void xpose(
    const float* __restrict__ X, short* __restrict__ xt) {
  const int b = blockIdx.x, r = blockIdx.y;   // r in 0..33 (halo coords)
  const int tid = threadIdx.x;
  const bool rin = (r >= 1) && (r <= 32);
  for (int idx = tid; idx < 34 * 256; idx += 256) {
    int cc = idx >> 8, c = idx & 255;
    float v = 0.f;
    if (rin && cc >= 1 && cc <= 32)
      v = X[((size_t)b * 256 + c) * 1024 + (r - 1) * 32 + (cc - 1)];
    xt[(((size_t)b * 34 + r) * 34 + cc) * 256 + c] = f2bs(v);
  }
}

// ---------------------------------------------------------------------------
// Prepass B: Wb[tap][o][c] bf16 from w_out[o][c][3][3].  589824 elements.
// grid 2304, block 256.
// ---------------------------------------------------------------------------
__global__ __launch_bounds__(256) void wpack(
    const float* __restrict__ Wc, short* __restrict__ Wb) {
  int idx = blockIdx.x * 256 + threadIdx.x;   // tap*65536 + o*256 + c
  int tap = idx >> 16;
  int rest = idx & 65535;
  int o = rest >> 8, c = rest & 255;
  Wb[idx] = f2bs(Wc[((size_t)o * 256 + c) * 9 + tap]);
}

// ---------------------------------------------------------------------------
// Kernel 1: QKV 1x1 conv as GEMM.  Epilogue emits MFMA-ready bf16:
//   qsb[bnh][q][d] (scaled) | ksb[bnh][key][d] | vtb[bnh][d][key]
// grid (16, 12, 8), block 256.
// ---------------------------------------------------------------------------
__global__ __launch_bounds__(256) void qkv_gemm(
    const float* __restrict__ W, const float* __restrict__ X,
    const float* __restrict__ bias,
    short* __restrict__ qsb, short* __restrict__ ksb, short* __restrict__ vtb) {
  const int b  = blockIdx.z;
  const int p0 = blockIdx.x * 64;
  const int o0 = blockIdx.y * 64;
  const int tid = threadIdx.x;
  const int tx = tid & 15, ty = tid >> 4;
  __shared__ float As[16][64];   // [k][o]
  __shared__ float Bs[16][64];   // [k][p]
  float acc[4][4] = {};
  const float* Xb = X + (size_t)b * 256 * 1024;
  for (int c0 = 0; c0 < 256; c0 += 16) {
    {
      int r = tid >> 2, c4 = (tid & 3) * 4;
      float4 w4 = *(const float4*)(W + (size_t)(o0 + r) * 256 + c0 + c4);
      As[c4 + 0][r] = w4.x; As[c4 + 1][r] = w4.y;
      As[c4 + 2][r] = w4.z; As[c4 + 3][r] = w4.w;
    }
    {
      int r = tid >> 4, cp = (tid & 15) * 4;
      float4 x4 = *(const float4*)(Xb + (size_t)(c0 + r) * 1024 + p0 + cp);
      *(float4*)&Bs[r][cp] = x4;
    }
    __syncthreads();
#pragma unroll
    for (int k = 0; k < 16; ++k) {
      float4 a4 = *(const float4*)&As[k][ty * 4];
      float4 b4 = *(const float4*)&Bs[k][tx * 4];
      float av[4] = {a4.x, a4.y, a4.z, a4.w};
      float bv[4] = {b4.x, b4.y, b4.z, b4.w};
#pragma unroll
      for (int i2 = 0; i2 < 4; ++i2)
#pragma unroll
        for (int j2 = 0; j2 < 4; ++j2)
          acc[i2][j2] += av[i2] * bv[j2];
    }
    __syncthreads();
  }
  const float scale = 0.17677669529663687f;  // 32^-0.5
#pragma unroll
  for (int i2 = 0; i2 < 4; ++i2) {
    int o = o0 + ty * 4 + i2;
    float bv = bias[o];
    int sect = o >> 8;                       // 0=q 1=k 2=v (block-uniform)
    int nh = (o >> 5) & 7, d = o & 31;
    size_t hb = ((size_t)(b * 8 + nh)) * 1024;   // bnh * 1024
    if (sect == 0) {
#pragma unroll
      for (int j2 = 0; j2 < 4; ++j2) {
        int p = p0 + tx * 4 + j2;
        qsb[(hb + p) * 32 + d] = f2bs((acc[i2][j2] + bv) * scale);
      }
    } else if (sect == 1) {
#pragma unroll
      for (int j2 = 0; j2 < 4; ++j2) {
        int p = p0 + tx * 4 + j2;
        ksb[(hb + p) * 32 + d] = f2bs(acc[i2][j2] + bv);
      }
    } else {
#pragma unroll
      for (int j2 = 0; j2 < 4; ++j2) {
        int p = p0 + tx * 4 + j2;
        vtb[hb * 32 + (size_t)d * 1024 + p] = f2bs(acc[i2][j2] + bv);
      }
    }
  }
}

// ---------------------------------------------------------------------------
// Kernel 2: MFMA flash attention (round 7, unchanged).  grid (16, 64),
// block 256 = 4 waves; 1 wave = 16 queries x 1024 keys.
// ---------------------------------------------------------------------------
__global__ __launch_bounds__(256, 4) void attn_mfma(
    const short* __restrict__ qsb, const short* __restrict__ ksb,
    const short* __restrict__ vtb,
    const float* __restrict__ relw_g, const float* __restrict__ relh_g,
    float* __restrict__ am) {
  const int tid = threadIdx.x;
  const int w = tid >> 6, lane = tid & 63;
  const int col = lane & 15, grp = lane >> 4;
  const int g8 = grp * 8;
  const int qt = blockIdx.x * 4 + w;       // q-tile 0..63
  const int bnh = blockIdx.y;
  const int q0 = qt * 16;
  const int i = qt >> 1;                   // query row, constant per wave
  const int j0 = (qt & 1) * 16;            // query col base

  const short* Qb = qsb + (size_t)bnh * 32768;
  const short* Kb = ksb + (size_t)bnh * 32768;
  const short* Vb = vtb + (size_t)bnh * 32768;

  __shared__ short Gh_s[4][64][16];  // [wave][m][q]  8KB
  __shared__ short Gw_s[4][64][16];  // [wave][m][q]  8KB
  __shared__ short P_s[4][16][40];   // [wave][q][key] pitch 40  5KB

  short8 a_q = *(const short8*)(Qb + (q0 + col) * 32 + g8);

  {
    const float* rels[2] = {relh_g, relw_g};
    short* gbase[2] = {&Gh_s[w][0][0], &Gw_s[w][0][0]};
#pragma unroll
    for (int tb = 0; tb < 2; ++tb) {
      const float* relg = rels[tb];
      short* Gb = gbase[tb];
#pragma unroll
      for (int t = 0; t < 4; ++t) {
        int m = col + 16 * t;
        int mc = m > 62 ? 62 : m;            // m=63 is junk, never read
        const float* rp = relg + mc * 32 + g8;
        float4 f0 = *(const float4*)rp;
        float4 f1 = *(const float4*)(rp + 4);
        short8 br;
        br[0] = f2bs(f0.x); br[1] = f2bs(f0.y);
        br[2] = f2bs(f0.z); br[3] = f2bs(f0.w);
        br[4] = f2bs(f1.x); br[5] = f2bs(f1.y);
        br[6] = f2bs(f1.z); br[7] = f2bs(f1.w);
        f32x4 d = __builtin_amdgcn_mfma_f32_16x16x32_bf16(
            a_q, br, (f32x4){0.f, 0.f, 0.f, 0.f}, 0, 0, 0);
        short4v o;
        o[0] = f2bs(d[0]); o[1] = f2bs(d[1]);
        o[2] = f2bs(d[2]); o[3] = f2bs(d[3]);
        *(short4v*)(Gb + m * 16 + grp * 4) = o;
      }
    }
  }
  __asm__ volatile("s_waitcnt lgkmcnt(0)" ::: "memory");

  short one_v = (col == 0) ? (short)0x3F80 : (short)0;
  short8 b_one = {one_v, one_v, one_v, one_v, one_v, one_v, one_v, one_v};

  f32x4 acc0 = {0.f, 0.f, 0.f, 0.f};
  f32x4 acc1 = {0.f, 0.f, 0.f, 0.f};
  f32x4 accl = {0.f, 0.f, 0.f, 0.f};

  short8 k0 = *(const short8*)(Kb + (0 * 32 + 0 * 16 + col) * 32 + g8);
  short8 k1 = *(const short8*)(Kb + (0 * 32 + 1 * 16 + col) * 32 + g8);
  short8 v0 = *(const short8*)(Vb + (0 * 16 + col) * 1024 + 0 * 32 + g8);
  short8 v1 = *(const short8*)(Vb + (1 * 16 + col) * 1024 + 0 * 32 + g8);

#pragma unroll 1
  for (int c = 0; c < 32; ++c) {
    short8 ck0 = k0, ck1 = k1, cv0 = v0, cv1 = v1;
    if (c + 1 < 32) {
      int kb = (c + 1) * 32;
      k0 = *(const short8*)(Kb + (kb + col) * 32 + g8);
      k1 = *(const short8*)(Kb + (kb + 16 + col) * 32 + g8);
      v0 = *(const short8*)(Vb + (0 * 16 + col) * 1024 + kb + g8);
      v1 = *(const short8*)(Vb + (1 * 16 + col) * 1024 + kb + g8);
    }
    f32x4 s0 = __builtin_amdgcn_mfma_f32_16x16x32_bf16(
        a_q, ck0, (f32x4){0.f, 0.f, 0.f, 0.f}, 0, 0, 0);
    f32x4 s1 = __builtin_amdgcn_mfma_f32_16x16x32_bf16(
        a_q, ck1, (f32x4){0.f, 0.f, 0.f, 0.f}, 0, 0, 0);
    int mh = c - i + 31;
    short4v ghv = *(const short4v*)&Gh_s[w][mh][grp * 4];
#pragma unroll
    for (int t = 0; t < 2; ++t) {
      f32x4 s = t ? s1 : s0;
      int y = t * 16 + col;
#pragma unroll
      for (int r = 0; r < 4; ++r) {
        int qrel = grp * 4 + r;
        int mw = y - j0 - qrel + 31;
        float lg = s[r] + bs2f(ghv[r]) + bs2f(Gw_s[w][mw][qrel]);
        P_s[w][qrel][y] = f2bs(__expf(lg));
      }
    }
    __asm__ volatile("s_waitcnt lgkmcnt(0)" ::: "memory");
    short8 a_p = *(const short8*)&P_s[w][col][g8];
    acc0 = __builtin_amdgcn_mfma_f32_16x16x32_bf16(a_p, cv0, acc0, 0, 0, 0);
    acc1 = __builtin_amdgcn_mfma_f32_16x16x32_bf16(a_p, cv1, acc1, 0, 0, 0);
    accl = __builtin_amdgcn_mfma_f32_16x16x32_bf16(a_p, b_one, accl, 0, 0, 0);
  }

  float* amb = am + (size_t)bnh * 32768;
#pragma unroll
  for (int r = 0; r < 4; ++r) {
    float lv = __shfl(accl[r], lane & 48);
    float rn = 1.0f / lv;
    int q = q0 + grp * 4 + r;
    amb[(size_t)col * 1024 + q] = acc0[r] * rn;
    amb[(size_t)(16 + col) * 1024 + q] = acc1[r] * rn;
  }
}

// ---------------------------------------------------------------------------
// Kernel 3: output projection GEMM, fp32 out channels [256,512).
// grid (16, 4, 8), block 256.
// ---------------------------------------------------------------------------
__global__ __launch_bounds__(256) void proj_gemm(
    const float* __restrict__ W, const float* __restrict__ Am,
    const float* __restrict__ bias, float* __restrict__ out) {
  const int b = blockIdx.z;
  const int p0 = blockIdx.x * 64;
  const int o0 = blockIdx.y * 64;
  const int tid = threadIdx.x;
  const int tx = tid & 15, ty = tid >> 4;
  __shared__ float As[16][64];
  __shared__ float Bs[16][64];
  float acc[4][4] = {};
  const float* Ab = Am + (size_t)b * 256 * 1024;
  for (int c0 = 0; c0 < 256; c0 += 16) {
    {
      int r = tid >> 2, c4 = (tid & 3) * 4;
      float4 w4 = *(const float4*)(W + (size_t)(o0 + r) * 256 + c0 + c4);
      As[c4 + 0][r] = w4.x; As[c4 + 1][r] = w4.y;
      As[c4 + 2][r] = w4.z; As[c4 + 3][r] = w4.w;
    }
    {
      int r = tid >> 4, cp = (tid & 15) * 4;
      float4 x4 = *(const float4*)(Ab + (size_t)(c0 + r) * 1024 + p0 + cp);
      *(float4*)&Bs[r][cp] = x4;
    }
    __syncthreads();
#pragma unroll
    for (int k = 0; k < 16; ++k) {
      float4 a4 = *(const float4*)&As[k][ty * 4];
      float4 b4 = *(const float4*)&Bs[k][tx * 4];
      float av[4] = {a4.x, a4.y, a4.z, a4.w};
      float bv[4] = {b4.x, b4.y, b4.z, b4.w};
#pragma unroll
      for (int i2 = 0; i2 < 4; ++i2)
#pragma unroll
        for (int j2 = 0; j2 < 4; ++j2)
          acc[i2][j2] += av[i2] * bv[j2];
    }
    __syncthreads();
  }
#pragma unroll
  for (int i2 = 0; i2 < 4; ++i2) {
    int o = o0 + ty * 4 + i2;
    float bv = bias[o];
    float4 r4 = make_float4(acc[i2][0] + bv, acc[i2][1] + bv,
                            acc[i2][2] + bv, acc[i2][3] + bv);
    *(float4*)&out[((size_t)b * 512 + 256 + o) * 1024 + p0 + tx * 4] = r4;
  }
}

// ---------------------------------------------------------------------------
// Kernel 4 (v4): MFMA implicit-GEMM 3x3 conv, depth-3 pipeline in NAMED
// registers, tail-peeled (no conditionals around loads).  grid (32,4,8),
// block 256 = 4 waves; 1 wave = 16 out-ch x 32 positions.  it = tap*8+ch,
// u=(tap*11)>>5, v=tap-3u (exact for tap<9).  __launch_bounds__(256,3):
// VGPR budget ~168 >> ~80 demand -> spilling impossible (round-9 lesson).
// ---------------------------------------------------------------------------
#define CONV_LOAD(n, A_, B0_, B1_)                                   \
  do {                                                               \
    const int t_ = (n) >> 3, ch_ = ((n) & 7) * 32;                   \
    const int u_ = (t_ * 11) >> 5, v_ = t_ - 3 * u_;                 \
    A_ = *(const short8*)(Wa + t_ * 65536 + ch_);                    \
    const short* pb_ = Xrow + (u_ * 34 + v_) * 256 + ch_;            \
    B0_ = *(const short8*)pb_;                                       \
    B1_ = *(const short8*)(pb_ + 4096);                              \
  } while (0)

__global__ __launch_bounds__(256, 3) void conv_mfma(
    const short* __restrict__ xt, const short* __restrict__ Wb,
    const float* __restrict__ bias, float* __restrict__ out) {
  const int tid = threadIdx.x;
  const int w = tid >> 6, lane = tid & 63;
  const int col = lane & 15, grp = lane >> 4, g8 = grp * 8;
  const int r0 = blockIdx.x;                 // image row 0..31
  const int o0 = blockIdx.y * 64 + w * 16;   // out-channel tile
  const int bb = blockIdx.z;

  const short* Wa   = Wb + (o0 + col) * 256 + g8;
  const short* Xrow = xt + (size_t)bb * 34 * 34 * 256
                         + (r0 * 34 + col) * 256 + g8;

  short8 A0, B00, B10, A1, B01, B11, A2, B02, B12;
  CONV_LOAD(0, A0, B00, B10);
  CONV_LOAD(1, A1, B01, B11);
  CONV_LOAD(2, A2, B02, B12);

  f32x4 acc0 = {0.f, 0.f, 0.f, 0.f};
  f32x4 acc1 = {0.f, 0.f, 0.f, 0.f};

#pragma unroll 1
  for (int it = 0; it < 69; it += 3) {       // consumes 0..68, prefetch 3..71
    short8 ca, cb0, cb1;
    ca = A0; cb0 = B00; cb1 = B10;
    CONV_LOAD(it + 3, A0, B00, B10);
    acc0 = __builtin_amdgcn_mfma_f32_16x16x32_bf16(ca, cb0, acc0, 0, 0, 0);
    acc1 = __builtin_amdgcn_mfma_f32_16x16x32_bf16(ca, cb1, acc1, 0, 0, 0);
    ca = A1; cb0 = B01; cb1 = B11;
    CONV_LOAD(it + 4, A1, B01, B11);
    acc0 = __builtin_amdgcn_mfma_f32_16x16x32_bf16(ca, cb0, acc0, 0, 0, 0);
    acc1 = __builtin_amdgcn_mfma_f32_16x16x32_bf16(ca, cb1, acc1, 0, 0, 0);
    ca = A2; cb0 = B02; cb1 = B12;
    CONV_LOAD(it + 5, A2, B02, B12);
    acc0 = __builtin_amdgcn_mfma_f32_16x16x32_bf16(ca, cb0, acc0, 0, 0, 0);
    acc1 = __builtin_amdgcn_mfma_f32_16x16x32_bf16(ca, cb1, acc1, 0, 0, 0);
  }
  // tail: iterations 69,70,71 already resident in the three slots
  acc0 = __builtin_amdgcn_mfma_f32_16x16x32_bf16(A0, B00, acc0, 0, 0, 0);
  acc1 = __builtin_amdgcn_mfma_f32_16x16x32_bf16(A0, B10, acc1, 0, 0, 0);
  acc0 = __builtin_amdgcn_mfma_f32_16x16x32_bf16(A1, B01, acc0, 0, 0, 0);
  acc1 = __builtin_amdgcn_mfma_f32_16x16x32_bf16(A1, B11, acc1, 0, 0, 0);
  acc0 = __builtin_amdgcn_mfma_f32_16x16x32_bf16(A2, B02, acc0, 0, 0, 0);
  acc1 = __builtin_amdgcn_mfma_f32_16x16x32_bf16(A2, B12, acc1, 0, 0, 0);

  float* ob = out + (size_t)bb * 512 * 1024;
#pragma unroll
  for (int r = 0; r < 4; ++r) {
    int o = o0 + grp * 4 + r;
    float bv = bias[o];
    ob[(size_t)o * 1024 + r0 * 32 + col]      = acc0[r] + bv;
    ob[(size_t)o * 1024 + r0 * 32 + 16 + col] = acc1[r] + bv;
  }
}

// ---------------------------------------------------------------------------
extern "C" void kernel_launch(void* const* d_in, const int* in_sizes, int n_in,
                              void* d_out, int out_size, void* d_ws, size_t ws_size,
                              hipStream_t stream) {
  const float* x      = (const float*)d_in[0];
  const float* w_qkv  = (const float*)d_in[1];
  const float* b_qkv  = (const float*)d_in[2];
  const float* w_attn = (const float*)d_in[3];
  const float* b_attn = (const float*)d_in[4];
  const float* w_out  = (const float*)d_in[5];
  const float* b_out  = (const float*)d_in[6];
  const float* relw   = (const float*)d_in[7];
  const float* relh   = (const float*)d_in[8];
  float* out = (float*)d_out;

  // ws: qsb bf16 4MB | ksb 4MB | vtb 4MB | am f32 8MB | xt bf16 ~4.74MB
  //     (at 20MB) | Wb bf16 ~1.18MB (at 25MB).  Total ~26.2MB.
  short* qsb = (short*)d_ws;
  short* ksb = qsb + (size_t)2 * 1024 * 1024;
  short* vtb = ksb + (size_t)2 * 1024 * 1024;
  float* am  = (float*)((char*)d_ws + (size_t)12 * 1024 * 1024);
  short* xt  = (short*)((char*)d_ws + (size_t)20 * 1024 * 1024);
  short* Wb  = (short*)((char*)d_ws + (size_t)25 * 1024 * 1024);

  xpose<<<dim3(8, 34), 256, 0, stream>>>(x, xt);
  wpack<<<2304, 256, 0, stream>>>(w_out, Wb);
  qkv_gemm<<<dim3(16, 12, 8), 256, 0, stream>>>(w_qkv, x, b_qkv, qsb, ksb, vtb);
  attn_mfma<<<dim3(16, 64), 256, 0, stream>>>(qsb, ksb, vtb, relw, relh, am);
  proj_gemm<<<dim3(16, 4, 8), 256, 0, stream>>>(w_attn, am, b_attn, out);
  conv_mfma<<<dim3(32, 4, 8), 256, 0, stream>>>(xt, Wb, b_out, out);
}

// Round 11
// 243.635 us; speedup vs baseline: 1.4057x; 1.2405x over previous
//
#include <hip/hip_runtime.h>
#include <hip/hip_bf16.h>

// Round-2 finding: ALL inputs and the output are FP32.
// Round-10 post-mortem: register-pipeline attempts (r9 arrays, r10 named
// regs) are both defeated: allocator either spills (154MB WRITE) or the
// scheduler re-sinks loads (VGPR 28).  Real bottleneck is line-gather BW:
// A/B frag loads touch 16 cache lines each (512B lane stride, 16B used).
// Round 11: stage X rows in LDS once per block (pitch 264 => bank-even
// ds_read_b128), A gets L1 reuse across each tap's 8 ch-chunks.

typedef __hip_bfloat16 bf16;
using short8 = __attribute__((ext_vector_type(8))) short;
using short4v = __attribute__((ext_vector_type(4))) short;
using f32x4 = __attribute__((ext_vector_type(4))) float;

__device__ __forceinline__ short f2bs(float f) {
  union { bf16 b; short s; } u; u.b = __float2bfloat16(f); return u.s;
}
__device__ __forceinline__ float bs2f(short s) {
  union { unsigned u; float f; } x; x.u = ((unsigned)(unsigned short)s) << 16;
  return x.f;
}

// ---------------------------------------------------------------------------
// Prepass A: xt[b][34][34][256] bf16 = x NCHW -> spatial-major channel-contig
// with zero halo ring (conv padding by layout).  grid (8, 34), block 256.
// ---------------------------------------------------------------------------
__global__ __launch_bounds__(256) void xpose(
    const float* __restrict__ X, short* __restrict__ xt) {
  const int b = blockIdx.x, r = blockIdx.y;   // r in 0..33 (halo coords)
  const int tid = threadIdx.x;
  const bool rin = (r >= 1) && (r <= 32);
  for (int idx = tid; idx < 34 * 256; idx += 256) {
    int cc = idx >> 8, c = idx & 255;
    float v = 0.f;
    if (rin && cc >= 1 && cc <= 32)
      v = X[((size_t)b * 256 + c) * 1024 + (r - 1) * 32 + (cc - 1)];
    xt[(((size_t)b * 34 + r) * 34 + cc) * 256 + c] = f2bs(v);
  }
}

// ---------------------------------------------------------------------------
// Prepass B: Wb[tap][o][c] bf16 from w_out[o][c][3][3].  589824 elements.
// grid 2304, block 256.
// ---------------------------------------------------------------------------
__global__ __launch_bounds__(256) void wpack(
    const float* __restrict__ Wc, short* __restrict__ Wb) {
  int idx = blockIdx.x * 256 + threadIdx.x;   // tap*65536 + o*256 + c
  int tap = idx >> 16;
  int rest = idx & 65535;
  int o = rest >> 8, c = rest & 255;
  Wb[idx] = f2bs(Wc[((size_t)o * 256 + c) * 9 + tap]);
}

// ---------------------------------------------------------------------------
// Kernel 1: QKV 1x1 conv as GEMM.  Epilogue emits MFMA-ready bf16:
//   qsb[bnh][q][d] (scaled) | ksb[bnh][key][d] | vtb[bnh][d][key]
// grid (16, 12, 8), block 256.
// ---------------------------------------------------------------------------
__global__ __launch_bounds__(256) void qkv_gemm(
    const float* __restrict__ W, const float* __restrict__ X,
    const float* __restrict__ bias,
    short* __restrict__ qsb, short* __restrict__ ksb, short* __restrict__ vtb) {
  const int b  = blockIdx.z;
  const int p0 = blockIdx.x * 64;
  const int o0 = blockIdx.y * 64;
  const int tid = threadIdx.x;
  const int tx = tid & 15, ty = tid >> 4;
  __shared__ float As[16][64];   // [k][o]
  __shared__ float Bs[16][64];   // [k][p]
  float acc[4][4] = {};
  const float* Xb = X + (size_t)b * 256 * 1024;
  for (int c0 = 0; c0 < 256; c0 += 16) {
    {
      int r = tid >> 2, c4 = (tid & 3) * 4;
      float4 w4 = *(const float4*)(W + (size_t)(o0 + r) * 256 + c0 + c4);
      As[c4 + 0][r] = w4.x; As[c4 + 1][r] = w4.y;
      As[c4 + 2][r] = w4.z; As[c4 + 3][r] = w4.w;
    }
    {
      int r = tid >> 4, cp = (tid & 15) * 4;
      float4 x4 = *(const float4*)(Xb + (size_t)(c0 + r) * 1024 + p0 + cp);
      *(float4*)&Bs[r][cp] = x4;
    }
    __syncthreads();
#pragma unroll
    for (int k = 0; k < 16; ++k) {
      float4 a4 = *(const float4*)&As[k][ty * 4];
      float4 b4 = *(const float4*)&Bs[k][tx * 4];
      float av[4] = {a4.x, a4.y, a4.z, a4.w};
      float bv[4] = {b4.x, b4.y, b4.z, b4.w};
#pragma unroll
      for (int i2 = 0; i2 < 4; ++i2)
#pragma unroll
        for (int j2 = 0; j2 < 4; ++j2)
          acc[i2][j2] += av[i2] * bv[j2];
    }
    __syncthreads();
  }
  const float scale = 0.17677669529663687f;  // 32^-0.5
#pragma unroll
  for (int i2 = 0; i2 < 4; ++i2) {
    int o = o0 + ty * 4 + i2;
    float bv = bias[o];
    int sect = o >> 8;                       // 0=q 1=k 2=v (block-uniform)
    int nh = (o >> 5) & 7, d = o & 31;
    size_t hb = ((size_t)(b * 8 + nh)) * 1024;   // bnh * 1024
    if (sect == 0) {
#pragma unroll
      for (int j2 = 0; j2 < 4; ++j2) {
        int p = p0 + tx * 4 + j2;
        qsb[(hb + p) * 32 + d] = f2bs((acc[i2][j2] + bv) * scale);
      }
    } else if (sect == 1) {
#pragma unroll
      for (int j2 = 0; j2 < 4; ++j2) {
        int p = p0 + tx * 4 + j2;
        ksb[(hb + p) * 32 + d] = f2bs(acc[i2][j2] + bv);
      }
    } else {
#pragma unroll
      for (int j2 = 0; j2 < 4; ++j2) {
        int p = p0 + tx * 4 + j2;
        vtb[hb * 32 + (size_t)d * 1024 + p] = f2bs(acc[i2][j2] + bv);
      }
    }
  }
}

// ---------------------------------------------------------------------------
// Kernel 2: MFMA flash attention (round 7, unchanged).  grid (16, 64),
// block 256 = 4 waves; 1 wave = 16 queries x 1024 keys.
// ---------------------------------------------------------------------------
__global__ __launch_bounds__(256, 4) void attn_mfma(
    const short* __restrict__ qsb, const short* __restrict__ ksb,
    const short* __restrict__ vtb,
    const float* __restrict__ relw_g, const float* __restrict__ relh_g,
    float* __restrict__ am) {
  const int tid = threadIdx.x;
  const int w = tid >> 6, lane = tid & 63;
  const int col = lane & 15, grp = lane >> 4;
  const int g8 = grp * 8;
  const int qt = blockIdx.x * 4 + w;       // q-tile 0..63
  const int bnh = blockIdx.y;
  const int q0 = qt * 16;
  const int i = qt >> 1;                   // query row, constant per wave
  const int j0 = (qt & 1) * 16;            // query col base

  const short* Qb = qsb + (size_t)bnh * 32768;
  const short* Kb = ksb + (size_t)bnh * 32768;
  const short* Vb = vtb + (size_t)bnh * 32768;

  __shared__ short Gh_s[4][64][16];  // [wave][m][q]  8KB
  __shared__ short Gw_s[4][64][16];  // [wave][m][q]  8KB
  __shared__ short P_s[4][16][40];   // [wave][q][key] pitch 40  5KB

  short8 a_q = *(const short8*)(Qb + (q0 + col) * 32 + g8);

  {
    const float* rels[2] = {relh_g, relw_g};
    short* gbase[2] = {&Gh_s[w][0][0], &Gw_s[w][0][0]};
#pragma unroll
    for (int tb = 0; tb < 2; ++tb) {
      const float* relg = rels[tb];
      short* Gb = gbase[tb];
#pragma unroll
      for (int t = 0; t < 4; ++t) {
        int m = col + 16 * t;
        int mc = m > 62 ? 62 : m;            // m=63 is junk, never read
        const float* rp = relg + mc * 32 + g8;
        float4 f0 = *(const float4*)rp;
        float4 f1 = *(const float4*)(rp + 4);
        short8 br;
        br[0] = f2bs(f0.x); br[1] = f2bs(f0.y);
        br[2] = f2bs(f0.z); br[3] = f2bs(f0.w);
        br[4] = f2bs(f1.x); br[5] = f2bs(f1.y);
        br[6] = f2bs(f1.z); br[7] = f2bs(f1.w);
        f32x4 d = __builtin_amdgcn_mfma_f32_16x16x32_bf16(
            a_q, br, (f32x4){0.f, 0.f, 0.f, 0.f}, 0, 0, 0);
        short4v o;
        o[0] = f2bs(d[0]); o[1] = f2bs(d[1]);
        o[2] = f2bs(d[2]); o[3] = f2bs(d[3]);
        *(short4v*)(Gb + m * 16 + grp * 4) = o;
      }
    }
  }
  __asm__ volatile("s_waitcnt lgkmcnt(0)" ::: "memory");

  short one_v = (col == 0) ? (short)0x3F80 : (short)0;
  short8 b_one = {one_v, one_v, one_v, one_v, one_v, one_v, one_v, one_v};

  f32x4 acc0 = {0.f, 0.f, 0.f, 0.f};
  f32x4 acc1 = {0.f, 0.f, 0.f, 0.f};
  f32x4 accl = {0.f, 0.f, 0.f, 0.f};

  short8 k0 = *(const short8*)(Kb + (0 * 32 + 0 * 16 + col) * 32 + g8);
  short8 k1 = *(const short8*)(Kb + (0 * 32 + 1 * 16 + col) * 32 + g8);
  short8 v0 = *(const short8*)(Vb + (0 * 16 + col) * 1024 + 0 * 32 + g8);
  short8 v1 = *(const short8*)(Vb + (1 * 16 + col) * 1024 + 0 * 32 + g8);

#pragma unroll 1
  for (int c = 0; c < 32; ++c) {
    short8 ck0 = k0, ck1 = k1, cv0 = v0, cv1 = v1;
    if (c + 1 < 32) {
      int kb = (c + 1) * 32;
      k0 = *(const short8*)(Kb + (kb + col) * 32 + g8);
      k1 = *(const short8*)(Kb + (kb + 16 + col) * 32 + g8);
      v0 = *(const short8*)(Vb + (0 * 16 + col) * 1024 + kb + g8);
      v1 = *(const short8*)(Vb + (1 * 16 + col) * 1024 + kb + g8);
    }
    f32x4 s0 = __builtin_amdgcn_mfma_f32_16x16x32_bf16(
        a_q, ck0, (f32x4){0.f, 0.f, 0.f, 0.f}, 0, 0, 0);
    f32x4 s1 = __builtin_amdgcn_mfma_f32_16x16x32_bf16(
        a_q, ck1, (f32x4){0.f, 0.f, 0.f, 0.f}, 0, 0, 0);
    int mh = c - i + 31;
    short4v ghv = *(const short4v*)&Gh_s[w][mh][grp * 4];
#pragma unroll
    for (int t = 0; t < 2; ++t) {
      f32x4 s = t ? s1 : s0;
      int y = t * 16 + col;
#pragma unroll
      for (int r = 0; r < 4; ++r) {
        int qrel = grp * 4 + r;
        int mw = y - j0 - qrel + 31;
        float lg = s[r] + bs2f(ghv[r]) + bs2f(Gw_s[w][mw][qrel]);
        P_s[w][qrel][y] = f2bs(__expf(lg));
      }
    }
    __asm__ volatile("s_waitcnt lgkmcnt(0)" ::: "memory");
    short8 a_p = *(const short8*)&P_s[w][col][g8];
    acc0 = __builtin_amdgcn_mfma_f32_16x16x32_bf16(a_p, cv0, acc0, 0, 0, 0);
    acc1 = __builtin_amdgcn_mfma_f32_16x16x32_bf16(a_p, cv1, acc1, 0, 0, 0);
    accl = __builtin_amdgcn_mfma_f32_16x16x32_bf16(a_p, b_one, accl, 0, 0, 0);
  }

  float* amb = am + (size_t)bnh * 32768;
#pragma unroll
  for (int r = 0; r < 4; ++r) {
    float lv = __shfl(accl[r], lane & 48);
    float rn = 1.0f / lv;
    int q = q0 + grp * 4 + r;
    amb[(size_t)col * 1024 + q] = acc0[r] * rn;
    amb[(size_t)(16 + col) * 1024 + q] = acc1[r] * rn;
  }
}

// ---------------------------------------------------------------------------
// Kernel 3: output projection GEMM, fp32 out channels [256,512).
// grid (16, 4, 8), block 256.
// ---------------------------------------------------------------------------
__global__ __launch_bounds__(256) void proj_gemm(
    const float* __restrict__ W, const float* __restrict__ Am,
    const float* __restrict__ bias, float* __restrict__ out) {
  const int b = blockIdx.z;
  const int p0 = blockIdx.x * 64;
  const int o0 = blockIdx.y * 64;
  const int tid = threadIdx.x;
  const int tx = tid & 15, ty = tid >> 4;
  __shared__ float As[16][64];
  __shared__ float Bs[16][64];
  float acc[4][4] = {};
  const float* Ab = Am + (size_t)b * 256 * 1024;
  for (int c0 = 0; c0 < 256; c0 += 16) {
    {
      int r = tid >> 2, c4 = (tid & 3) * 4;
      float4 w4 = *(const float4*)(W + (size_t)(o0 + r) * 256 + c0 + c4);
      As[c4 + 0][r] = w4.x; As[c4 + 1][r] = w4.y;
      As[c4 + 2][r] = w4.z; As[c4 + 3][r] = w4.w;
    }
    {
      int r = tid >> 4, cp = (tid & 15) * 4;
      float4 x4 = *(const float4*)(Ab + (size_t)(c0 + r) * 1024 + p0 + cp);
      *(float4*)&Bs[r][cp] = x4;
    }
    __syncthreads();
#pragma unroll
    for (int k = 0; k < 16; ++k) {
      float4 a4 = *(const float4*)&As[k][ty * 4];
      float4 b4 = *(const float4*)&Bs[k][tx * 4];
      float av[4] = {a4.x, a4.y, a4.z, a4.w};
      float bv[4] = {b4.x, b4.y, b4.z, b4.w};
#pragma unroll
      for (int i2 = 0; i2 < 4; ++i2)
#pragma unroll
        for (int j2 = 0; j2 < 4; ++j2)
          acc[i2][j2] += av[i2] * bv[j2];
    }
    __syncthreads();
  }
#pragma unroll
  for (int i2 = 0; i2 < 4; ++i2) {
    int o = o0 + ty * 4 + i2;
    float bv = bias[o];
    float4 r4 = make_float4(acc[i2][0] + bv, acc[i2][1] + bv,
                            acc[i2][2] + bv, acc[i2][3] + bv);
    *(float4*)&out[((size_t)b * 512 + 256 + o) * 1024 + p0 + tx * 4] = r4;
  }
}

// ---------------------------------------------------------------------------
// Kernel 4 (v5): LDS-staged MFMA implicit-GEMM 3x3 conv.
// grid (32 rows, 2 o-halves, 8 b) = 512 blocks, block 256 = 4 waves.
// Stage 3 halo rows (3x34x256 bf16, LDS pitch 264 -> bank-even b128 reads)
// once per block; 72 k-steps x (2 global A + 2 LDS B + 4 MFMA).
// B-frag line-gathers eliminated (LDS); A lines reused across each tap's
// 8 ch-chunks via L1.  1 wave = 2 o-tiles of 16 x 32 positions.
// ---------------------------------------------------------------------------
__global__ __launch_bounds__(256) void conv_mfma(
    const short* __restrict__ xt, const short* __restrict__ Wb,
    const float* __restrict__ bias, float* __restrict__ out) {
  const int tid = threadIdx.x;
  const int w = tid >> 6, lane = tid & 63;
  const int col = lane & 15, grp = lane >> 4, g8 = grp * 8;
  const int r0 = blockIdx.x;            // output row 0..31
  const int oh = blockIdx.y;            // o half 0/1
  const int bb = blockIdx.z;

  __shared__ short xs[3][34][264];      // pitch 264: even bank spread for b128

  {
    const short* src = xt + (((size_t)bb * 34 + r0) * 34) * 256;
    for (int g = tid; g < 3264; g += 256) {       // 3*34*32 8-short groups
      int row = g / 1088;                          // 34*32
      int rem = g - row * 1088;
      int cc = rem >> 5, chg = rem & 31;
      short8 v = *(const short8*)(src + (row * 34 + cc) * 256 + chg * 8);
      *(short8*)&xs[row][cc][chg * 8] = v;
    }
  }
  __syncthreads();

  const int ob0 = oh * 128 + w * 16;    // first o-tile
  const int ob1 = ob0 + 64;             // second o-tile
  const short* Wa0 = Wb + (ob0 + col) * 256 + g8;
  const short* Wa1 = Wb + (ob1 + col) * 256 + g8;

  f32x4 acc00 = {0.f, 0.f, 0.f, 0.f};   // ot0, p = col
  f32x4 acc01 = {0.f, 0.f, 0.f, 0.f};   // ot0, p = col+16
  f32x4 acc10 = {0.f, 0.f, 0.f, 0.f};   // ot1, p = col
  f32x4 acc11 = {0.f, 0.f, 0.f, 0.f};   // ot1, p = col+16

#pragma unroll 1
  for (int tap = 0; tap < 9; ++tap) {
    const int u = (tap * 11) >> 5, v = tap - 3 * u;   // exact for tap<9
    const short* wa0 = Wa0 + tap * 65536;
    const short* wa1 = Wa1 + tap * 65536;
    const short* xb0 = &xs[u][col + v][g8];
    const short* xb1 = &xs[u][col + 16 + v][g8];
#pragma unroll
    for (int c8 = 0; c8 < 8; ++c8) {
      const int chb = c8 * 32;
      short8 a0 = *(const short8*)(wa0 + chb);
      short8 a1 = *(const short8*)(wa1 + chb);
      short8 b0 = *(const short8*)(xb0 + chb);
      short8 b1 = *(const short8*)(xb1 + chb);
      acc00 = __builtin_amdgcn_mfma_f32_16x16x32_bf16(a0, b0, acc00, 0, 0, 0);
      acc01 = __builtin_amdgcn_mfma_f32_16x16x32_bf16(a0, b1, acc01, 0, 0, 0);
      acc10 = __builtin_amdgcn_mfma_f32_16x16x32_bf16(a1, b0, acc10, 0, 0, 0);
      acc11 = __builtin_amdgcn_mfma_f32_16x16x32_bf16(a1, b1, acc11, 0, 0, 0);
    }
  }

  float* ob = out + (size_t)bb * 512 * 1024 + r0 * 32;
#pragma unroll
  for (int r = 0; r < 4; ++r) {
    int o0 = ob0 + grp * 4 + r;
    int o1 = ob1 + grp * 4 + r;
    float bv0 = bias[o0], bv1 = bias[o1];
    ob[(size_t)o0 * 1024 + col]      = acc00[r] + bv0;
    ob[(size_t)o0 * 1024 + 16 + col] = acc01[r] + bv0;
    ob[(size_t)o1 * 1024 + col]      = acc10[r] + bv1;
    ob[(size_t)o1 * 1024 + 16 + col] = acc11[r] + bv1;
  }
}

// ---------------------------------------------------------------------------
extern "C" void kernel_launch(void* const* d_in, const int* in_sizes, int n_in,
                              void* d_out, int out_size, void* d_ws, size_t ws_size,
                              hipStream_t stream) {
  const float* x      = (const float*)d_in[0];
  const float* w_qkv  = (const float*)d_in[1];
  const float* b_qkv  = (const float*)d_in[2];
  const float* w_attn = (const float*)d_in[3];
  const float* b_attn = (const float*)d_in[4];
  const float* w_out  = (const float*)d_in[5];
  const float* b_out  = (const float*)d_in[6];
  const float* relw   = (const float*)d_in[7];
  const float* relh   = (const float*)d_in[8];
  float* out = (float*)d_out;

  // ws: qsb bf16 4MB | ksb 4MB | vtb 4MB | am f32 8MB | xt bf16 ~4.74MB
  //     (at 20MB) | Wb bf16 ~1.18MB (at 25MB).  Total ~26.2MB.
  short* qsb = (short*)d_ws;
  short* ksb = qsb + (size_t)2 * 1024 * 1024;
  short* vtb = ksb + (size_t)2 * 1024 * 1024;
  float* am  = (float*)((char*)d_ws + (size_t)12 * 1024 * 1024);
  short* xt  = (short*)((char*)d_ws + (size_t)20 * 1024 * 1024);
  short* Wb  = (short*)((char*)d_ws + (size_t)25 * 1024 * 1024);

  xpose<<<dim3(8, 34), 256, 0, stream>>>(x, xt);
  wpack<<<2304, 256, 0, stream>>>(w_out, Wb);
  qkv_gemm<<<dim3(16, 12, 8), 256, 0, stream>>>(w_qkv, x, b_qkv, qsb, ksb, vtb);
  attn_mfma<<<dim3(16, 64), 256, 0, stream>>>(qsb, ksb, vtb, relw, relh, am);
  proj_gemm<<<dim3(16, 4, 8), 256, 0, stream>>>(w_attn, am, b_attn, out);
  conv_mfma<<<dim3(32, 2, 8), 256, 0, stream>>>(xt, Wb, b_out, out);
}